// Round 2
// baseline (1979.586 us; speedup 1.0000x reference)
//
#include <hip/hip_runtime.h>
#include <stdint.h>

// ---------------- problem constants ----------------
constexpr int TT = 128;    // time steps
constexpr int BB = 256;    // batch
constexpr int EE = 1024;   // embedding dim
constexpr int LL = 1024;   // hidden dim
constexpr int NG = 4096;   // 4 gates * LL
constexpr int VV = 95;     // vocab

typedef short bf16x8 __attribute__((ext_vector_type(8)));
typedef float f32x4  __attribute__((ext_vector_type(4)));

__device__ __forceinline__ unsigned short f2bf(float f) {
    unsigned int u = __builtin_bit_cast(unsigned int, f);
    unsigned int r = (u + 0x7FFFu + ((u >> 16) & 1u)) >> 16;
    return (unsigned short)r;
}
__device__ __forceinline__ float sigmoidf_(float x) {
    return 1.0f / (1.0f + __expf(-x));
}
__device__ __forceinline__ float tanhf_(float x) {
    // 1 - 2/(e^{2x}+1): saturates cleanly, no NaN for large |x|
    return 1.0f - 2.0f / (__expf(2.0f * x) + 1.0f);
}

// ---------------- prep: permute+convert recurrent weights ----------------
// Wperm[(lt*64 + nl)*1024 + k] = bf16( W_gate[nl>>4][ (lt*16 + (nl&15))*2048 + 1024 + k ] )
__global__ void prep_weights(const float* __restrict__ Wf, const float* __restrict__ Wi,
                             const float* __restrict__ Wo, const float* __restrict__ Wc,
                             unsigned short* __restrict__ Wperm) {
    int idx = blockIdx.x * 256 + threadIdx.x;
    const int total = NG * LL;  // 4096*1024
    for (; idx < total; idx += gridDim.x * 256) {
        int row = idx >> 10;        // 0..4095
        int k   = idx & 1023;
        int nl  = row & 63;
        int lt  = row >> 6;
        int gate = nl >> 4;
        int l = lt * 16 + (nl & 15);
        const float* W = (gate == 0) ? Wf : (gate == 1) ? Wi : (gate == 2) ? Wo : Wc;
        Wperm[idx] = f2bf(W[l * 2048 + 1024 + k]);
    }
}

// ---------------- prep: gate_pre[v][n] = emb[v] . W_n[0:1024] + b[n]  (fp32) ----------------
__global__ void prep_gate_pre(const float* __restrict__ emb,
                              const float* __restrict__ Wf, const float* __restrict__ Wi,
                              const float* __restrict__ Wo, const float* __restrict__ Wc,
                              const float* __restrict__ bfv, const float* __restrict__ biv,
                              const float* __restrict__ bov, const float* __restrict__ bcv,
                              float* __restrict__ gate_pre) {
    __shared__ float embs[VV][132];
    __shared__ float Ws[16][132];
    const int tid = threadIdx.x;
    const int n0 = blockIdx.x * 16;        // 256 blocks, 16 n each, never crosses a gate
    const int gate = n0 >> 10;
    const float* W    = (gate == 0) ? Wf  : (gate == 1) ? Wi  : (gate == 2) ? Wo  : Wc;
    const float* bias = (gate == 0) ? bfv : (gate == 1) ? biv : (gate == 2) ? bov : bcv;

    float acc[6] = {0.f, 0.f, 0.f, 0.f, 0.f, 0.f};

    for (int kc = 0; kc < 8; ++kc) {
        // stage emb chunk: 95 x 128 floats
        for (int q = tid; q < VV * 32; q += 256) {
            int v = q >> 5, kq = q & 31;
            float4 val = *(const float4*)(emb + v * EE + kc * 128 + kq * 4);
            *(float4*)&embs[v][kq * 4] = val;
        }
        // stage W chunk: 16 x 128 floats (embedding half: cols 0..1023)
        for (int q = tid; q < 16 * 32; q += 256) {
            int nl = q >> 5, kq = q & 31;
            int l = (n0 + nl) & 1023;
            float4 val = *(const float4*)(W + l * 2048 + kc * 128 + kq * 4);
            *(float4*)&Ws[nl][kq * 4] = val;
        }
        __syncthreads();
        #pragma unroll
        for (int s = 0; s < 6; ++s) {
            int oi = tid + s * 256;
            if (oi < VV * 16) {
                int v = oi >> 4, nl = oi & 15;
                float a = 0.f;
                #pragma unroll 8
                for (int k = 0; k < 128; k += 4) {
                    float4 ev = *(const float4*)&embs[v][k];
                    float4 wv = *(const float4*)&Ws[nl][k];
                    a += ev.x * wv.x + ev.y * wv.y + ev.z * wv.z + ev.w * wv.w;
                }
                acc[s] += a;
            }
        }
        __syncthreads();
    }
    #pragma unroll
    for (int s = 0; s < 6; ++s) {
        int oi = tid + s * 256;
        if (oi < VV * 16) {
            int v = oi >> 4, nl = oi & 15;
            gate_pre[v * NG + n0 + nl] = acc[s] + bias[(n0 + nl) & 1023];
        }
    }
}

// ---------------- prep: init h (bf16 from input) and c (=0) ----------------
__global__ void init_state(const float* __restrict__ h_init,
                           unsigned short* __restrict__ h0, float* __restrict__ c) {
    int idx = blockIdx.x * 256 + threadIdx.x;   // 1024 blocks * 256 = 262144 = BB*LL
    h0[idx] = f2bf(h_init[idx]);
    c[idx] = 0.f;
}

// ---------------- per-timestep fused GEMM + cell update ----------------
// grid 256 blocks (bt = blk>>6 in 0..3 batch-tile of 64, lt = blk&63 l-tile of 16)
// block computes g[64 b][4 gates][16 l] = h_tile @ Wperm_tile, then the cell update.
__global__ __launch_bounds__(256)
void lstm_step(const unsigned short* __restrict__ Wperm,
               const float* __restrict__ gate_pre,
               const int* __restrict__ x_t,          // x + t*BB
               const unsigned short* __restrict__ h_in,
               unsigned short* __restrict__ h_out,
               float* __restrict__ c_ws,
               float* __restrict__ out_t) {          // out + t*BB*LL
    __shared__ unsigned short Ah[64][72];   // h tile   (pad 8 -> 144B row stride, 16B aligned)
    __shared__ unsigned short Bw[64][72];   // W tile (n-major)

    const int tid  = threadIdx.x;
    const int lane = tid & 63;
    const int wid  = tid >> 6;              // wave id = M-subtile (16 rows each)
    const int blk  = blockIdx.x;
    const int bt   = blk >> 6;              // 0..3
    const int lt   = blk & 63;              // 0..63

    f32x4 acc0 = {0.f, 0.f, 0.f, 0.f};
    f32x4 acc1 = {0.f, 0.f, 0.f, 0.f};
    f32x4 acc2 = {0.f, 0.f, 0.f, 0.f};
    f32x4 acc3 = {0.f, 0.f, 0.f, 0.f};

    // staging: each thread moves 2x16B for A and B per K-chunk of 64
    const int srow = tid >> 2;              // 0..63
    const int scol = (tid & 3) << 4;        // 0,16,32,48 elements
    const unsigned short* gA = h_in  + (size_t)(bt * 64 + srow) * LL + scol;
    const unsigned short* gB = Wperm + (size_t)(lt * 64 + srow) * LL + scol;

    // fragment addressing (mfma_f32_16x16x32_bf16):
    // A[m][k]: m = lane&15, k = (lane>>4)*8 + j ; B[k][n]: n = lane&15, same k
    const int frow = lane & 15;
    const int fk   = (lane >> 4) * 8;

    for (int kb = 0; kb < 16; ++kb) {
        const uint4 a0 = *(const uint4*)(gA + kb * 64);
        const uint4 a1 = *(const uint4*)(gA + kb * 64 + 8);
        const uint4 b0 = *(const uint4*)(gB + kb * 64);
        const uint4 b1 = *(const uint4*)(gB + kb * 64 + 8);
        *(uint4*)&Ah[srow][scol]     = a0;
        *(uint4*)&Ah[srow][scol + 8] = a1;
        *(uint4*)&Bw[srow][scol]     = b0;
        *(uint4*)&Bw[srow][scol + 8] = b1;
        __syncthreads();
        #pragma unroll
        for (int kk = 0; kk < 2; ++kk) {
            const int k0 = kk * 32 + fk;
            bf16x8 af  = *(const bf16x8*)&Ah[wid * 16 + frow][k0];
            bf16x8 bw0 = *(const bf16x8*)&Bw[ 0 + frow][k0];
            bf16x8 bw1 = *(const bf16x8*)&Bw[16 + frow][k0];
            bf16x8 bw2 = *(const bf16x8*)&Bw[32 + frow][k0];
            bf16x8 bw3 = *(const bf16x8*)&Bw[48 + frow][k0];
            acc0 = __builtin_amdgcn_mfma_f32_16x16x32_bf16(af, bw0, acc0, 0, 0, 0);
            acc1 = __builtin_amdgcn_mfma_f32_16x16x32_bf16(af, bw1, acc1, 0, 0, 0);
            acc2 = __builtin_amdgcn_mfma_f32_16x16x32_bf16(af, bw2, acc2, 0, 0, 0);
            acc3 = __builtin_amdgcn_mfma_f32_16x16x32_bf16(af, bw3, acc3, 0, 0, 0);
        }
        __syncthreads();
    }

    // epilogue: C/D layout col=lane&15 (=n within 16), row=(lane>>4)*4+reg
    const int mbase = wid * 16 + (lane >> 4) * 4;
    const int l     = lt * 16 + (lane & 15);
    #pragma unroll
    for (int r = 0; r < 4; ++r) {
        const int b = bt * 64 + mbase + r;
        const int v = x_t[b];
        const float* gp = gate_pre + (size_t)v * NG;
        float g0 = acc0[r] + gp[l];             // f
        float g1 = acc1[r] + gp[LL + l];        // i
        float g2 = acc2[r] + gp[2 * LL + l];    // o
        float g3 = acc3[r] + gp[3 * LL + l];    // c~
        float fg = sigmoidf_(g0);
        float ig = sigmoidf_(g1);
        float og = sigmoidf_(g2);
        float cg = tanhf_(g3);
        float cold = c_ws[(size_t)b * LL + l];
        float cn = fg * cold + ig * cg;
        float hn = og * tanhf_(cn);
        c_ws[(size_t)b * LL + l] = cn;
        out_t[(size_t)b * LL + l] = hn;
        h_out[(size_t)b * LL + l] = f2bf(hn);
    }
}

// ---------------- launch ----------------
extern "C" void kernel_launch(void* const* d_in, const int* in_sizes, int n_in,
                              void* d_out, int out_size, void* d_ws, size_t ws_size,
                              hipStream_t stream) {
    const int*   x      = (const int*)d_in[0];
    const float* h_init = (const float*)d_in[1];
    const float* emb    = (const float*)d_in[2];
    const float* Wf     = (const float*)d_in[3];
    const float* bfv    = (const float*)d_in[4];
    const float* Wi     = (const float*)d_in[5];
    const float* biv    = (const float*)d_in[6];
    const float* Wo     = (const float*)d_in[7];
    const float* bov    = (const float*)d_in[8];
    const float* Wc     = (const float*)d_in[9];
    const float* bcv    = (const float*)d_in[10];
    float* out = (float*)d_out;

    char* ws = (char*)d_ws;
    unsigned short* Wperm    = (unsigned short*)ws;                          // 8 MB
    float*          gate_pre = (float*)(ws + 8388608);                       // 1.49 MB
    float*          c_ws     = (float*)(ws + 8388608 + 1556480);             // 1 MB
    unsigned short* hb0      = (unsigned short*)(ws + 8388608 + 1556480 + 1048576);
    unsigned short* hb1      = hb0 + BB * LL;

    prep_weights<<<1024, 256, 0, stream>>>(Wf, Wi, Wo, Wc, Wperm);
    prep_gate_pre<<<256, 256, 0, stream>>>(emb, Wf, Wi, Wo, Wc, bfv, biv, bov, bcv, gate_pre);
    init_state<<<1024, 256, 0, stream>>>(h_init, hb0, c_ws);

    unsigned short* hin = hb0;
    unsigned short* hout = hb1;
    for (int t = 0; t < TT; ++t) {
        lstm_step<<<256, 256, 0, stream>>>(Wperm, gate_pre, x + t * BB,
                                           hin, hout, c_ws,
                                           out + (size_t)t * BB * LL);
        unsigned short* tmp = hin; hin = hout; hout = tmp;
    }
}